// Round 14
// baseline (109.416 us; speedup 1.0000x reference)
//
#include <hip/hip_runtime.h>
#include <math.h>

#define NN 50000
#define NE 800000
#define BSHIFT 7
#define BNODES 128                      // nodes per bucket
#define NB 391                          // ceil(NN / BNODES)
#define NBB 200                         // binning blocks
#define EPB 4000                        // edges per binning block (NBB*EPB == NE)
#define PRE_BLOCKS 196                  // ceil(NN/256)

__device__ __forceinline__ float elu1(float v) {
    return v > 0.0f ? v : expm1f(v);
}

// ---- fused: bin1 histogram (blocks 0..NBB-1) + pre1 projection (blocks NBB..) ----
// HM holds RAW counts (bucket-major: HM[b*NBB + blk]).
__global__ void setup_kernel(const int* __restrict__ ei, int* __restrict__ HM,
                             const float* __restrict__ x,
                             const float* __restrict__ Wp,   // [65][16]
                             const float* __restrict__ bp,   // [16]
                             float* __restrict__ P1) {
    __shared__ unsigned hist[NB];
    __shared__ float sW[64 * 16];
    __shared__ float sb[16];
    if (blockIdx.x < NBB) {
        for (int i = threadIdx.x; i < NB; i += 256) hist[i] = 0;
        __syncthreads();
        int base = blockIdx.x * EPB;
        for (int i = threadIdx.x; i < EPB; i += 256) {
            int d = ei[NE + base + i];
            atomicAdd(&hist[d >> BSHIFT], 1u);
        }
        __syncthreads();
        for (int b = threadIdx.x; b < NB; b += 256)
            HM[b * NBB + blockIdx.x] = (int)hist[b];
    } else {
        for (int i = threadIdx.x; i < 64 * 16; i += 256) sW[i] = Wp[i];
        if (threadIdx.x < 16) sb[threadIdx.x] = bp[threadIdx.x];
        __syncthreads();
        int n = (blockIdx.x - NBB) * 256 + threadIdx.x;
        if (n >= NN) return;
        float acc[16];
#pragma unroll
        for (int k = 0; k < 16; ++k) acc[k] = sb[k];
        const float4* xr = (const float4*)(x + (size_t)n * 64);
#pragma unroll
        for (int j4 = 0; j4 < 16; ++j4) {
            float4 xv = xr[j4];
            const float* w = &sW[j4 * 4 * 16];
#pragma unroll
            for (int k = 0; k < 16; ++k) acc[k] += xv.x * w[k];
#pragma unroll
            for (int k = 0; k < 16; ++k) acc[k] += xv.y * w[16 + k];
#pragma unroll
            for (int k = 0; k < 16; ++k) acc[k] += xv.z * w[32 + k];
#pragma unroll
            for (int k = 0; k < 16; ++k) acc[k] += xv.w * w[48 + k];
        }
        float4* o = (float4*)(P1 + (size_t)n * 16);
        o[0] = make_float4(acc[0], acc[1], acc[2], acc[3]);
        o[1] = make_float4(acc[4], acc[5], acc[6], acc[7]);
        o[2] = make_float4(acc[8], acc[9], acc[10], acc[11]);
        o[3] = make_float4(acc[12], acc[13], acc[14], acc[15]);
    }
}

// ---- bin2 (self-scanning): per-block recompute of row prefixes + bucket bases,
//      then scatter records into bucket-grouped sp1. ----
__global__ void bin2_kernel(const int* __restrict__ ei, const float* __restrict__ ea,
                            const int* __restrict__ HM,
                            int* __restrict__ bstart,
                            int2* __restrict__ sp1) {
    __shared__ int s[512];
    __shared__ unsigned cur[NB];
    int tid = threadIdx.x;
    int blk = blockIdx.x;
    int total = 0, pre = 0;
    if (tid < NB) {
        const int* row = HM + tid * NBB;
        for (int k = 0; k < NBB; ++k) {
            if (k == blk) pre = total;
            total += row[k];
        }
    }
    s[tid] = total;
    __syncthreads();
#pragma unroll
    for (int off = 1; off < 512; off <<= 1) {
        int tmp = (tid >= off) ? s[tid - off] : 0;
        __syncthreads();
        s[tid] += tmp;
        __syncthreads();
    }
    if (tid < NB) {
        int base = s[tid] - total;
        cur[tid] = (unsigned)(base + pre);
        if (blk == 0) bstart[tid] = base;
    }
    if (blk == 0 && tid == 0) bstart[NB] = s[511];
    __syncthreads();
    int base = blk * EPB;
    for (int i = tid; i < EPB; i += 512) {
        int e = base + i;
        int d = ei[NE + e];
        int srcv = ei[e];
        int b = d >> BSHIFT;
        int dl = d & (BNODES - 1);
        unsigned pos = atomicAdd(&cur[b], 1u);
        sp1[pos] = make_int2(srcv | (dl << 16), __float_as_int(ea[e]));
    }
}

// ---- per-bucket counting sort by local node, DEGREE-RANKED ----
__global__ void sort_kernel(const int2* __restrict__ sp1,
                            const int* __restrict__ bstart,
                            int2* __restrict__ sp2,
                            int* __restrict__ start,
                            int* __restrict__ perm) {
    __shared__ unsigned hist[BNODES];
    __shared__ int s[256];
    __shared__ unsigned dcnt[64];
    __shared__ unsigned dcur[64];
    __shared__ int dlof[BNODES];
    __shared__ int soff[BNODES];
    __shared__ unsigned cur[BNODES];
    __shared__ int sdeg[BNODES];
    int tid = threadIdx.x;
    int b = blockIdx.x;
    int e0 = bstart[b], e1 = bstart[b + 1];
    if (tid < BNODES) hist[tid] = 0;
    if (tid < 64) dcnt[tid] = 0;
    __syncthreads();
    for (int i = e0 + tid; i < e1; i += 256) {
        int dl = (sp1[i].x >> 16) & (BNODES - 1);
        atomicAdd(&hist[dl], 1u);
    }
    __syncthreads();
    if (tid < BNODES) {
        int key = min((int)hist[tid], 63);
        atomicAdd(&dcnt[key], 1u);
    }
    __syncthreads();
    int v = (tid < 64) ? (int)dcnt[tid] : 0;
    s[tid] = v;
    __syncthreads();
#pragma unroll
    for (int off = 1; off < 64; off <<= 1) {
        int tmp = (tid >= off) ? s[tid - off] : 0;
        __syncthreads();
        s[tid] += tmp;
        __syncthreads();
    }
    if (tid < 64) dcur[tid] = (unsigned)(s[tid] - v);
    __syncthreads();
    if (tid < BNODES) {
        int key = min((int)hist[tid], 63);
        int rank = (int)atomicAdd(&dcur[key], 1u);
        dlof[rank] = tid;
    }
    __syncthreads();
    if (tid < BNODES) sdeg[tid] = (int)hist[dlof[tid]];
    __syncthreads();
    int v2 = (tid < BNODES) ? sdeg[tid] : 0;
    s[tid] = v2;
    __syncthreads();
#pragma unroll
    for (int off = 1; off < 128; off <<= 1) {
        int tmp = (tid >= off) ? s[tid - off] : 0;
        __syncthreads();
        s[tid] += tmp;
        __syncthreads();
    }
    if (tid < BNODES) {
        int off = s[tid] - v2;
        soff[tid] = off;
        start[b * BNODES + tid] = e0 + off;
        perm[b * BNODES + tid] = b * BNODES + dlof[tid];
    }
    __syncthreads();
    if (tid < BNODES) cur[dlof[tid]] = (unsigned)(e0 + soff[tid]);
    if (b == NB - 1 && tid == 0) start[NB * BNODES] = e1;
    __syncthreads();
    for (int i = e0 + tid; i < e1; i += 256) {
        int2 rec = sp1[i];
        int dl = (rec.x >> 16) & (BNODES - 1);
        int pos = (int)atomicAdd(&cur[dl], 1u);
        sp2[pos] = make_int2(rec.x & 0xFFFF, rec.y);
    }
}

// ---- fused gather-max + node MLP: 16 lanes/node (4 parity quads x dim quad),
//      2-edge batch, coalesced quad load + butterfly exchange-add ----
// Inner loop identical to the proven R10 kernel; only edge scheduling differs:
// parity hi in 0..3, stride 4 (batch stride 8). One extra merge (xor 8).
template <int MODE>
__global__ void __launch_bounds__(256, 4)
gather_kernel(const long long* __restrict__ sp, // [NE] rank-sorted (src|ea)
              const int* __restrict__ start,   // [NB*BNODES+1], rank-indexed
              const int* __restrict__ perm,    // [NB*BNODES] rank -> node id
              const float* __restrict__ Pin,   // [NN][16]
              const float* __restrict__ wl,    // [16]
              const float* __restrict__ Wn,    // [16][16]
              const float* __restrict__ bn,    // [16]
              const float* __restrict__ Wo,    // [16][16]
              const float* __restrict__ bo,    // [16]
              const float* __restrict__ Wpn,   // [17][16] (MODE 0)
              const float* __restrict__ bpn,   // [16] (MODE 0)
              float* __restrict__ out) {
    __shared__ float swl[16], sbn[16], sbo[16], sbpn[16];
    __shared__ float sWnT[16][17];      // transposed + padded: sWnT[c][j] = Wn[j][c]
    __shared__ float sWo[256], sWpn[256];
    __shared__ float sAgg[16][17];
    int tid = threadIdx.x;
    if (tid < 256) {
        sWnT[tid & 15][tid >> 4] = Wn[tid];
        sWo[tid] = Wo[tid];
        if (MODE == 0) sWpn[tid] = Wpn[tid];
    }
    if (tid < 16) {
        swl[tid] = wl[tid]; sbn[tid] = bn[tid]; sbo[tid] = bo[tid];
        if (MODE == 0) sbpn[tid] = bpn[tid];
    }
    __syncthreads();

    int l  = tid >> 4;       // local rank 0..15
    int g  = tid & 3;        // j-group / output-group 0..3
    int hi = (tid >> 2) & 3; // edge-parity quad 0..3
    int r = blockIdx.x * 16 + l;         // rank index (< NB*BNODES = 50048... 3128*16)
    int n = perm[r];                     // actual node id
    bool valid = (n < NN);

    float acc[4] = {-INFINITY, -INFINITY, -INFINITY, -INFINITY};
    int s0 = start[r], s1 = start[r + 1];

    float wl0 = swl[g * 4 + 0], wl1 = swl[g * 4 + 1],
          wl2 = swl[g * 4 + 2], wl3 = swl[g * 4 + 3];
    float bn0 = sbn[g * 4 + 0], bn1 = sbn[g * 4 + 1],
          bn2 = sbn[g * 4 + 2], bn3 = sbn[g * 4 + 3];
    bool g1 = (g & 1) != 0, g2 = (g & 2) != 0;

    // preload this lane's 64 Wn weights into registers (static indices only)
    float wreg[64];
#pragma unroll
    for (int c = 0; c < 16; ++c) {
#pragma unroll
        for (int j = 0; j < 4; ++j) wreg[c * 4 + j] = sWnT[c][g * 4 + j];
    }

    int s = s0 + hi;         // parity quads: edges s0+hi, +4, +8, ...
    while (s < s1) {
        // batch of 2 edges: s and (s+4 clamped) — duplicate is a no-op under max
        int sB = (s + 4 < s1) ? (s + 4) : s;
        long long rA = sp[s];
        long long rB = sp[sB];
        int srcA = (int)(rA & 0xFFFFFFFFll);
        int srcB = (int)(rB & 0xFFFFFFFFll);
        float4 qA = ((const float4*)(Pin + (size_t)srcA * 16))[g];
        float4 qB = ((const float4*)(Pin + (size_t)srcB * 16))[g];
        float aA = __int_as_float((int)(rA >> 32));
        float aB = __int_as_float((int)(rB >> 32));
        s += 8;

#pragma unroll
        for (int e = 0; e < 2; ++e) {
            float4 cv = e ? qB : qA;
            float a = e ? aB : aA;
            float t0 = fmaxf(fmaf(a, wl0, cv.x), 0.0f);
            float t1 = fmaxf(fmaf(a, wl1, cv.y), 0.0f);
            float t2 = fmaxf(fmaf(a, wl2, cv.z), 0.0f);
            float t3 = fmaxf(fmaf(a, wl3, cv.w), 0.0f);
            float m[16];
#pragma unroll
            for (int c = 0; c < 16; ++c) {
                float o = t0 * wreg[c * 4 + 0];
                o = fmaf(t1, wreg[c * 4 + 1], o);
                o = fmaf(t2, wreg[c * 4 + 2], o);
                o = fmaf(t3, wreg[c * 4 + 3], o);
                m[c] = o;
            }
            // butterfly step 1 (xor 2)
            float h[8];
#pragma unroll
            for (int c = 0; c < 8; ++c) {
                float send = g2 ? m[c] : m[c + 8];
                float recv = __shfl_xor(send, 2, 64);
                h[c] = (g2 ? m[c + 8] : m[c]) + recv;
            }
            // butterfly step 2 (xor 1)
            float send, recv, r0, r1, r2, r3;
            send = g1 ? h[0] : h[4]; recv = __shfl_xor(send, 1, 64); r0 = (g1 ? h[4] : h[0]) + recv;
            send = g1 ? h[1] : h[5]; recv = __shfl_xor(send, 1, 64); r1 = (g1 ? h[5] : h[1]) + recv;
            send = g1 ? h[2] : h[6]; recv = __shfl_xor(send, 1, 64); r2 = (g1 ? h[6] : h[2]) + recv;
            send = g1 ? h[3] : h[7]; recv = __shfl_xor(send, 1, 64); r3 = (g1 ? h[7] : h[3]) + recv;
            acc[0] = fmaxf(acc[0], r0 + bn0);
            acc[1] = fmaxf(acc[1], r1 + bn1);
            acc[2] = fmaxf(acc[2], r2 + bn2);
            acc[3] = fmaxf(acc[3], r3 + bn3);
        }
    }
    // merge the four edge-parity quads (lanes within the 16-lane node group)
#pragma unroll
    for (int q = 0; q < 4; ++q) acc[q] = fmaxf(acc[q], __shfl_xor(acc[q], 4, 64));
#pragma unroll
    for (int q = 0; q < 4; ++q) acc[q] = fmaxf(acc[q], __shfl_xor(acc[q], 8, 64));

    bool empty = (s1 == s0);
    if (hi == 0) {
#pragma unroll
        for (int q = 0; q < 4; ++q) sAgg[l][g * 4 + q] = empty ? 0.0f : acc[q];
    }
    __syncthreads();

    if (MODE == 0) {
        float h[4];
#pragma unroll
        for (int q = 0; q < 4; ++q) {
            int c = g * 4 + q;
            float o = sbo[c];
#pragma unroll
            for (int j = 0; j < 16; ++j) o = fmaf(sAgg[l][j], sWo[j * 16 + c], o);
            h[q] = elu1(elu1(o));
        }
        __syncthreads();
        if (hi == 0) {
#pragma unroll
            for (int q = 0; q < 4; ++q) sAgg[l][g * 4 + q] = h[q];
        }
        __syncthreads();
        float p[4];
#pragma unroll
        for (int q = 0; q < 4; ++q) {
            int c = g * 4 + q;
            float o = sbpn[c];
#pragma unroll
            for (int k = 0; k < 16; ++k) o = fmaf(sAgg[l][k], sWpn[k * 16 + c], o);
            p[q] = o;
        }
        if (valid && hi == 0) {
            float4* op = (float4*)(out + (size_t)n * 16 + g * 4);
            *op = make_float4(p[0], p[1], p[2], p[3]);
        }
    } else {
        float oo[4];
#pragma unroll
        for (int q = 0; q < 4; ++q) {
            int c = g * 4 + q;
            float o = sbo[c];
#pragma unroll
            for (int j = 0; j < 16; ++j) o = fmaf(sAgg[l][j], sWo[j * 16 + c], o);
            oo[q] = o;
        }
        __syncthreads();
        if (hi == 0) {
#pragma unroll
            for (int q = 0; q < 4; ++q) sAgg[l][g * 4 + q] = oo[q];
        }
        __syncthreads();
        float mx = -INFINITY;
#pragma unroll
        for (int j = 0; j < 16; ++j) mx = fmaxf(mx, sAgg[l][j]);
        float sum = 0.0f;
#pragma unroll
        for (int j = 0; j < 16; ++j) sum += expf(sAgg[l][j] - mx);
        float ls = logf(sum) + mx;
        if (valid && hi == 0) {
            float4* op = (float4*)(out + (size_t)n * 16 + g * 4);
            *op = make_float4(oo[0] - ls, oo[1] - ls, oo[2] - ls, oo[3] - ls);
        }
    }
}

extern "C" void kernel_launch(void* const* d_in, const int* in_sizes, int n_in,
                              void* d_out, int out_size, void* d_ws, size_t ws_size,
                              hipStream_t stream) {
    const float* x         = (const float*)d_in[0];
    const float* edge_attr = (const float*)d_in[1];
    const int*   edge_index= (const int*)  d_in[2];
    const float* W_pre1 = (const float*)d_in[3];
    const float* b_pre1 = (const float*)d_in[4];
    const float* W_net1 = (const float*)d_in[5];
    const float* b_net1 = (const float*)d_in[6];
    const float* W_out1 = (const float*)d_in[7];
    const float* b_out1 = (const float*)d_in[8];
    const float* W_pre2 = (const float*)d_in[9];
    const float* b_pre2 = (const float*)d_in[10];
    const float* W_net2 = (const float*)d_in[11];
    const float* b_net2 = (const float*)d_in[12];
    const float* W_out2 = (const float*)d_in[13];
    const float* b_out2 = (const float*)d_in[14];

    char* ws = (char*)d_ws;
    int2*  sp1    = (int2*) (ws);                   // 6,400,000 B
    int2*  sp2    = (int2*) (ws + 6400000);         // 6,400,000 B
    float* P1     = (float*)(ws + 12800000);        // 3,200,000 B
    float* P2     = (float*)(ws + 16000000);        // 3,200,000 B
    int*   HM     = (int*)  (ws + 19200000);        // 312,800 B
    int*   bstart = (int*)  (ws + 19520000);        // 1,568 B
    int*   start  = (int*)  (ws + 19528000);        // (NB*128+1)*4 = 200,196 B
    int*   perm   = (int*)  (ws + 19728256);        // NB*128*4 = 200,192 B

    const int GATH_BLOCKS = (NB * BNODES) / 16;     // 3128 (rank space, 16 lanes/node)

    // ----- setup: bin1 histogram + pre1 projection, concurrent -----
    setup_kernel<<<NBB + PRE_BLOCKS, 256, 0, stream>>>(edge_index, HM, x, W_pre1, b_pre1, P1);
    // ----- bin2: self-scan + scatter -----
    bin2_kernel<<<NBB, 512, 0, stream>>>(edge_index, edge_attr, HM, bstart, sp1);
    sort_kernel<<<NB, 256, 0, stream>>>(sp1, bstart, sp2, start, perm);

    // ----- layer 1 -----
    gather_kernel<0><<<GATH_BLOCKS, 256, 0, stream>>>((const long long*)sp2, start, perm, P1,
        W_pre1 + 64 * 16, W_net1, b_net1, W_out1, b_out1, W_pre2, b_pre2, P2);

    // ----- layer 2 -----
    gather_kernel<1><<<GATH_BLOCKS, 256, 0, stream>>>((const long long*)sp2, start, perm, P2,
        W_pre2 + 16 * 16, W_net2, b_net2, W_out2, b_out2, nullptr, nullptr,
        (float*)d_out);
}

// Round 15
// 108.141 us; speedup vs baseline: 1.0118x; 1.0118x over previous
//
#include <hip/hip_runtime.h>
#include <math.h>

#define NN 50000
#define NE 800000
#define BSHIFT 7
#define BNODES 128                      // nodes per bucket
#define NB 391                          // ceil(NN / BNODES)
#define NBB 200                         // binning blocks
#define EPB 4000                        // edges per binning block (NBB*EPB == NE)
#define PRE_BLOCKS 196                  // ceil(NN/256)

__device__ __forceinline__ float elu1(float v) {
    return v > 0.0f ? v : expm1f(v);
}

// ---- fused: bin1 histogram (blocks 0..NBB-1) + pre1 projection (blocks NBB..) ----
// HM holds RAW counts (bucket-major: HM[b*NBB + blk]).
__global__ void setup_kernel(const int* __restrict__ ei, int* __restrict__ HM,
                             const float* __restrict__ x,
                             const float* __restrict__ Wp,   // [65][16]
                             const float* __restrict__ bp,   // [16]
                             float* __restrict__ P1) {
    __shared__ unsigned hist[NB];
    __shared__ float sW[64 * 16];
    __shared__ float sb[16];
    if (blockIdx.x < NBB) {
        for (int i = threadIdx.x; i < NB; i += 256) hist[i] = 0;
        __syncthreads();
        int base = blockIdx.x * EPB;
        for (int i = threadIdx.x; i < EPB; i += 256) {
            int d = ei[NE + base + i];
            atomicAdd(&hist[d >> BSHIFT], 1u);
        }
        __syncthreads();
        for (int b = threadIdx.x; b < NB; b += 256)
            HM[b * NBB + blockIdx.x] = (int)hist[b];
    } else {
        for (int i = threadIdx.x; i < 64 * 16; i += 256) sW[i] = Wp[i];
        if (threadIdx.x < 16) sb[threadIdx.x] = bp[threadIdx.x];
        __syncthreads();
        int n = (blockIdx.x - NBB) * 256 + threadIdx.x;
        if (n >= NN) return;
        float acc[16];
#pragma unroll
        for (int k = 0; k < 16; ++k) acc[k] = sb[k];
        const float4* xr = (const float4*)(x + (size_t)n * 64);
#pragma unroll
        for (int j4 = 0; j4 < 16; ++j4) {
            float4 xv = xr[j4];
            const float* w = &sW[j4 * 4 * 16];
#pragma unroll
            for (int k = 0; k < 16; ++k) acc[k] += xv.x * w[k];
#pragma unroll
            for (int k = 0; k < 16; ++k) acc[k] += xv.y * w[16 + k];
#pragma unroll
            for (int k = 0; k < 16; ++k) acc[k] += xv.z * w[32 + k];
#pragma unroll
            for (int k = 0; k < 16; ++k) acc[k] += xv.w * w[48 + k];
        }
        float4* o = (float4*)(P1 + (size_t)n * 16);
        o[0] = make_float4(acc[0], acc[1], acc[2], acc[3]);
        o[1] = make_float4(acc[4], acc[5], acc[6], acc[7]);
        o[2] = make_float4(acc[8], acc[9], acc[10], acc[11]);
        o[3] = make_float4(acc[12], acc[13], acc[14], acc[15]);
    }
}

// ---- bin2 (self-scanning): per-block recompute of row prefixes + bucket bases,
//      then scatter records into bucket-grouped sp1. ----
__global__ void bin2_kernel(const int* __restrict__ ei, const float* __restrict__ ea,
                            const int* __restrict__ HM,
                            int* __restrict__ bstart,
                            int2* __restrict__ sp1) {
    __shared__ int s[512];
    __shared__ unsigned cur[NB];
    int tid = threadIdx.x;
    int blk = blockIdx.x;
    int total = 0, pre = 0;
    if (tid < NB) {
        const int* row = HM + tid * NBB;
        for (int k = 0; k < NBB; ++k) {
            if (k == blk) pre = total;
            total += row[k];
        }
    }
    s[tid] = total;
    __syncthreads();
#pragma unroll
    for (int off = 1; off < 512; off <<= 1) {
        int tmp = (tid >= off) ? s[tid - off] : 0;
        __syncthreads();
        s[tid] += tmp;
        __syncthreads();
    }
    if (tid < NB) {
        int base = s[tid] - total;
        cur[tid] = (unsigned)(base + pre);
        if (blk == 0) bstart[tid] = base;
    }
    if (blk == 0 && tid == 0) bstart[NB] = s[511];
    __syncthreads();
    int base = blk * EPB;
    for (int i = tid; i < EPB; i += 512) {
        int e = base + i;
        int d = ei[NE + e];
        int srcv = ei[e];
        int b = d >> BSHIFT;
        int dl = d & (BNODES - 1);
        unsigned pos = atomicAdd(&cur[b], 1u);
        sp1[pos] = make_int2(srcv | (dl << 16), __float_as_int(ea[e]));
    }
}

// ---- per-bucket counting sort by local node, DEGREE-RANKED ----
__global__ void sort_kernel(const int2* __restrict__ sp1,
                            const int* __restrict__ bstart,
                            int2* __restrict__ sp2,
                            int* __restrict__ start,
                            int* __restrict__ perm) {
    __shared__ unsigned hist[BNODES];
    __shared__ int s[256];
    __shared__ unsigned dcnt[64];
    __shared__ unsigned dcur[64];
    __shared__ int dlof[BNODES];
    __shared__ int soff[BNODES];
    __shared__ unsigned cur[BNODES];
    __shared__ int sdeg[BNODES];
    int tid = threadIdx.x;
    int b = blockIdx.x;
    int e0 = bstart[b], e1 = bstart[b + 1];
    if (tid < BNODES) hist[tid] = 0;
    if (tid < 64) dcnt[tid] = 0;
    __syncthreads();
    for (int i = e0 + tid; i < e1; i += 256) {
        int dl = (sp1[i].x >> 16) & (BNODES - 1);
        atomicAdd(&hist[dl], 1u);
    }
    __syncthreads();
    if (tid < BNODES) {
        int key = min((int)hist[tid], 63);
        atomicAdd(&dcnt[key], 1u);
    }
    __syncthreads();
    int v = (tid < 64) ? (int)dcnt[tid] : 0;
    s[tid] = v;
    __syncthreads();
#pragma unroll
    for (int off = 1; off < 64; off <<= 1) {
        int tmp = (tid >= off) ? s[tid - off] : 0;
        __syncthreads();
        s[tid] += tmp;
        __syncthreads();
    }
    if (tid < 64) dcur[tid] = (unsigned)(s[tid] - v);
    __syncthreads();
    if (tid < BNODES) {
        int key = min((int)hist[tid], 63);
        int rank = (int)atomicAdd(&dcur[key], 1u);
        dlof[rank] = tid;
    }
    __syncthreads();
    if (tid < BNODES) sdeg[tid] = (int)hist[dlof[tid]];
    __syncthreads();
    int v2 = (tid < BNODES) ? sdeg[tid] : 0;
    s[tid] = v2;
    __syncthreads();
#pragma unroll
    for (int off = 1; off < 128; off <<= 1) {
        int tmp = (tid >= off) ? s[tid - off] : 0;
        __syncthreads();
        s[tid] += tmp;
        __syncthreads();
    }
    if (tid < BNODES) {
        int off = s[tid] - v2;
        soff[tid] = off;
        start[b * BNODES + tid] = e0 + off;
        perm[b * BNODES + tid] = b * BNODES + dlof[tid];
    }
    __syncthreads();
    if (tid < BNODES) cur[dlof[tid]] = (unsigned)(e0 + soff[tid]);
    if (b == NB - 1 && tid == 0) start[NB * BNODES] = e1;
    __syncthreads();
    for (int i = e0 + tid; i < e1; i += 256) {
        int2 rec = sp1[i];
        int dl = (rec.x >> 16) & (BNODES - 1);
        int pos = (int)atomicAdd(&cur[dl], 1u);
        sp2[pos] = make_int2(rec.x & 0xFFFF, rec.y);
    }
}

// ---- fused gather-max + node MLP: 8 lanes/node (R13-proven), 4-edge batch with
//      COALESCED rec loads (lane g loads rec s+2g, shfl-broadcast to quad) ----
// 16-lane variant regressed (R14); keep 8. Per 4 edges: 1 coalesced rec load
// + 4 coalesced P quad-loads (VMEM 8->5 insts), 4-deep latency batch.
template <int MODE>
__global__ void __launch_bounds__(256, 4)
gather_kernel(const long long* __restrict__ sp, // [NE] rank-sorted (src|ea)
              const int* __restrict__ start,   // [NB*BNODES+1], rank-indexed
              const int* __restrict__ perm,    // [NB*BNODES] rank -> node id
              const float* __restrict__ Pin,   // [NN][16]
              const float* __restrict__ wl,    // [16]
              const float* __restrict__ Wn,    // [16][16]
              const float* __restrict__ bn,    // [16]
              const float* __restrict__ Wo,    // [16][16]
              const float* __restrict__ bo,    // [16]
              const float* __restrict__ Wpn,   // [17][16] (MODE 0)
              const float* __restrict__ bpn,   // [16] (MODE 0)
              float* __restrict__ out) {
    __shared__ float swl[16], sbn[16], sbo[16], sbpn[16];
    __shared__ float sWnT[16][17];      // transposed + padded: sWnT[c][j] = Wn[j][c]
    __shared__ float sWo[256], sWpn[256];
    __shared__ float sAgg[32][17];
    int tid = threadIdx.x;
    if (tid < 256) {
        sWnT[tid & 15][tid >> 4] = Wn[tid];
        sWo[tid] = Wo[tid];
        if (MODE == 0) sWpn[tid] = Wpn[tid];
    }
    if (tid < 16) {
        swl[tid] = wl[tid]; sbn[tid] = bn[tid]; sbo[tid] = bo[tid];
        if (MODE == 0) sbpn[tid] = bpn[tid];
    }
    __syncthreads();

    int l  = tid >> 3;       // local rank 0..31
    int g  = tid & 3;        // j-group / output-group 0..3
    int hi = (tid >> 2) & 1; // edge-parity quad 0/1
    int wlane = tid & 63;    // lane within wave
    int qbase = wlane & ~3;  // quad base lane
    int r = blockIdx.x * 32 + l;
    int n = perm[r];
    bool valid = (n < NN);

    float acc[4] = {-INFINITY, -INFINITY, -INFINITY, -INFINITY};
    int s0 = start[r], s1 = start[r + 1];

    float wl0 = swl[g * 4 + 0], wl1 = swl[g * 4 + 1],
          wl2 = swl[g * 4 + 2], wl3 = swl[g * 4 + 3];
    float bn0 = sbn[g * 4 + 0], bn1 = sbn[g * 4 + 1],
          bn2 = sbn[g * 4 + 2], bn3 = sbn[g * 4 + 3];
    bool g1 = (g & 1) != 0, g2 = (g & 2) != 0;

    // preload this lane's 64 Wn weights into registers (static indices only)
    float wreg[64];
#pragma unroll
    for (int c = 0; c < 16; ++c) {
#pragma unroll
        for (int j = 0; j < 4; ++j) wreg[c * 4 + j] = sWnT[c][g * 4 + j];
    }

    int s = s0 + hi;         // quad 0: even edges; quad 1: odd edges (stride 2)
    while (s < s1) {
        // 4-edge batch: edges s, s+2, s+4, s+6 (clamped; duplicates are max-no-ops).
        // Lane g loads rec for edge s+2g -> 32B coalesced per quad; shfl broadcasts.
        int a = s + 2 * g;
        if (a >= s1) a = s1 - 1;
        long long myrec = sp[a];
        long long r0_ = __shfl(myrec, qbase + 0, 64);
        long long r1_ = __shfl(myrec, qbase + 1, 64);
        long long r2_ = __shfl(myrec, qbase + 2, 64);
        long long r3_ = __shfl(myrec, qbase + 3, 64);
        int src0 = (int)(r0_ & 0xFFFFFFFFll);
        int src1 = (int)(r1_ & 0xFFFFFFFFll);
        int src2 = (int)(r2_ & 0xFFFFFFFFll);
        int src3 = (int)(r3_ & 0xFFFFFFFFll);
        float4 q0 = ((const float4*)(Pin + (size_t)src0 * 16))[g];
        float4 q1 = ((const float4*)(Pin + (size_t)src1 * 16))[g];
        float4 q2 = ((const float4*)(Pin + (size_t)src2 * 16))[g];
        float4 q3 = ((const float4*)(Pin + (size_t)src3 * 16))[g];
        float a0 = __int_as_float((int)(r0_ >> 32));
        float a1 = __int_as_float((int)(r1_ >> 32));
        float a2 = __int_as_float((int)(r2_ >> 32));
        float a3 = __int_as_float((int)(r3_ >> 32));
        s += 8;

#pragma unroll
        for (int e = 0; e < 4; ++e) {
            float4 cv = (e == 0) ? q0 : (e == 1) ? q1 : (e == 2) ? q2 : q3;
            float aa = (e == 0) ? a0 : (e == 1) ? a1 : (e == 2) ? a2 : a3;
            float t0 = fmaxf(fmaf(aa, wl0, cv.x), 0.0f);
            float t1 = fmaxf(fmaf(aa, wl1, cv.y), 0.0f);
            float t2 = fmaxf(fmaf(aa, wl2, cv.z), 0.0f);
            float t3 = fmaxf(fmaf(aa, wl3, cv.w), 0.0f);
            float m[16];
#pragma unroll
            for (int c = 0; c < 16; ++c) {
                float o = t0 * wreg[c * 4 + 0];
                o = fmaf(t1, wreg[c * 4 + 1], o);
                o = fmaf(t2, wreg[c * 4 + 2], o);
                o = fmaf(t3, wreg[c * 4 + 3], o);
                m[c] = o;
            }
            // butterfly step 1 (xor 2)
            float h[8];
#pragma unroll
            for (int c = 0; c < 8; ++c) {
                float send = g2 ? m[c] : m[c + 8];
                float recv = __shfl_xor(send, 2, 64);
                h[c] = (g2 ? m[c + 8] : m[c]) + recv;
            }
            // butterfly step 2 (xor 1)
            float send, recv, rr0, rr1, rr2, rr3;
            send = g1 ? h[0] : h[4]; recv = __shfl_xor(send, 1, 64); rr0 = (g1 ? h[4] : h[0]) + recv;
            send = g1 ? h[1] : h[5]; recv = __shfl_xor(send, 1, 64); rr1 = (g1 ? h[5] : h[1]) + recv;
            send = g1 ? h[2] : h[6]; recv = __shfl_xor(send, 1, 64); rr2 = (g1 ? h[6] : h[2]) + recv;
            send = g1 ? h[3] : h[7]; recv = __shfl_xor(send, 1, 64); rr3 = (g1 ? h[7] : h[3]) + recv;
            acc[0] = fmaxf(acc[0], rr0 + bn0);
            acc[1] = fmaxf(acc[1], rr1 + bn1);
            acc[2] = fmaxf(acc[2], rr2 + bn2);
            acc[3] = fmaxf(acc[3], rr3 + bn3);
        }
    }
    // merge the two edge-parity quads
#pragma unroll
    for (int q = 0; q < 4; ++q) acc[q] = fmaxf(acc[q], __shfl_xor(acc[q], 4, 64));

    bool empty = (s1 == s0);
#pragma unroll
    for (int q = 0; q < 4; ++q) sAgg[l][g * 4 + q] = empty ? 0.0f : acc[q];
    __syncthreads();

    if (MODE == 0) {
        float h[4];
#pragma unroll
        for (int q = 0; q < 4; ++q) {
            int c = g * 4 + q;
            float o = sbo[c];
#pragma unroll
            for (int j = 0; j < 16; ++j) o = fmaf(sAgg[l][j], sWo[j * 16 + c], o);
            h[q] = elu1(elu1(o));
        }
        __syncthreads();
        if (hi == 0) {
#pragma unroll
            for (int q = 0; q < 4; ++q) sAgg[l][g * 4 + q] = h[q];
        }
        __syncthreads();
        float p[4];
#pragma unroll
        for (int q = 0; q < 4; ++q) {
            int c = g * 4 + q;
            float o = sbpn[c];
#pragma unroll
            for (int k = 0; k < 16; ++k) o = fmaf(sAgg[l][k], sWpn[k * 16 + c], o);
            p[q] = o;
        }
        if (valid && hi == 0) {
            float4* op = (float4*)(out + (size_t)n * 16 + g * 4);
            *op = make_float4(p[0], p[1], p[2], p[3]);
        }
    } else {
        float oo[4];
#pragma unroll
        for (int q = 0; q < 4; ++q) {
            int c = g * 4 + q;
            float o = sbo[c];
#pragma unroll
            for (int j = 0; j < 16; ++j) o = fmaf(sAgg[l][j], sWo[j * 16 + c], o);
            oo[q] = o;
        }
        __syncthreads();
        if (hi == 0) {
#pragma unroll
            for (int q = 0; q < 4; ++q) sAgg[l][g * 4 + q] = oo[q];
        }
        __syncthreads();
        float mx = -INFINITY;
#pragma unroll
        for (int j = 0; j < 16; ++j) mx = fmaxf(mx, sAgg[l][j]);
        float sum = 0.0f;
#pragma unroll
        for (int j = 0; j < 16; ++j) sum += expf(sAgg[l][j] - mx);
        float ls = logf(sum) + mx;
        if (valid && hi == 0) {
            float4* op = (float4*)(out + (size_t)n * 16 + g * 4);
            *op = make_float4(oo[0] - ls, oo[1] - ls, oo[2] - ls, oo[3] - ls);
        }
    }
}

extern "C" void kernel_launch(void* const* d_in, const int* in_sizes, int n_in,
                              void* d_out, int out_size, void* d_ws, size_t ws_size,
                              hipStream_t stream) {
    const float* x         = (const float*)d_in[0];
    const float* edge_attr = (const float*)d_in[1];
    const int*   edge_index= (const int*)  d_in[2];
    const float* W_pre1 = (const float*)d_in[3];
    const float* b_pre1 = (const float*)d_in[4];
    const float* W_net1 = (const float*)d_in[5];
    const float* b_net1 = (const float*)d_in[6];
    const float* W_out1 = (const float*)d_in[7];
    const float* b_out1 = (const float*)d_in[8];
    const float* W_pre2 = (const float*)d_in[9];
    const float* b_pre2 = (const float*)d_in[10];
    const float* W_net2 = (const float*)d_in[11];
    const float* b_net2 = (const float*)d_in[12];
    const float* W_out2 = (const float*)d_in[13];
    const float* b_out2 = (const float*)d_in[14];

    char* ws = (char*)d_ws;
    int2*  sp1    = (int2*) (ws);                   // 6,400,000 B
    int2*  sp2    = (int2*) (ws + 6400000);         // 6,400,000 B
    float* P1     = (float*)(ws + 12800000);        // 3,200,000 B
    float* P2     = (float*)(ws + 16000000);        // 3,200,000 B
    int*   HM     = (int*)  (ws + 19200000);        // 312,800 B
    int*   bstart = (int*)  (ws + 19520000);        // 1,568 B
    int*   start  = (int*)  (ws + 19528000);        // (NB*128+1)*4 = 200,196 B
    int*   perm   = (int*)  (ws + 19728256);        // NB*128*4 = 200,192 B

    const int GATH_BLOCKS = (NB * BNODES) / 32;     // 1564 (rank space, 8 lanes/node)

    // ----- setup: bin1 histogram + pre1 projection, concurrent -----
    setup_kernel<<<NBB + PRE_BLOCKS, 256, 0, stream>>>(edge_index, HM, x, W_pre1, b_pre1, P1);
    // ----- bin2: self-scan + scatter -----
    bin2_kernel<<<NBB, 512, 0, stream>>>(edge_index, edge_attr, HM, bstart, sp1);
    sort_kernel<<<NB, 256, 0, stream>>>(sp1, bstart, sp2, start, perm);

    // ----- layer 1 -----
    gather_kernel<0><<<GATH_BLOCKS, 256, 0, stream>>>((const long long*)sp2, start, perm, P1,
        W_pre1 + 64 * 16, W_net1, b_net1, W_out1, b_out1, W_pre2, b_pre2, P2);

    // ----- layer 2 -----
    gather_kernel<1><<<GATH_BLOCKS, 256, 0, stream>>>((const long long*)sp2, start, perm, P2,
        W_pre2 + 16 * 16, W_net2, b_net2, W_out2, b_out2, nullptr, nullptr,
        (float*)d_out);
}

// Round 16
// 93.405 us; speedup vs baseline: 1.1714x; 1.1578x over previous
//
#include <hip/hip_runtime.h>
#include <math.h>

#define NN 50000
#define NE 800000
#define BSHIFT 7
#define BNODES 128                      // nodes per bucket
#define NB 391                          // ceil(NN / BNODES)
#define NBB 200                         // binning blocks
#define EPB 4000                        // edges per binning block (NBB*EPB == NE)
#define PRE_BLOCKS 196                  // ceil(NN/256)

__device__ __forceinline__ float elu1(float v) {
    return v > 0.0f ? v : expm1f(v);
}

// ---- fused: bin1 histogram (blocks 0..NBB-1) + pre1 projection (blocks NBB..) ----
// HM holds RAW counts (bucket-major: HM[b*NBB + blk]).
__global__ void setup_kernel(const int* __restrict__ ei, int* __restrict__ HM,
                             const float* __restrict__ x,
                             const float* __restrict__ Wp,   // [65][16]
                             const float* __restrict__ bp,   // [16]
                             float* __restrict__ P1) {
    __shared__ unsigned hist[NB];
    __shared__ float sW[64 * 16];
    __shared__ float sb[16];
    if (blockIdx.x < NBB) {
        for (int i = threadIdx.x; i < NB; i += 256) hist[i] = 0;
        __syncthreads();
        int base = blockIdx.x * EPB;
        for (int i = threadIdx.x; i < EPB; i += 256) {
            int d = ei[NE + base + i];
            atomicAdd(&hist[d >> BSHIFT], 1u);
        }
        __syncthreads();
        for (int b = threadIdx.x; b < NB; b += 256)
            HM[b * NBB + blockIdx.x] = (int)hist[b];
    } else {
        for (int i = threadIdx.x; i < 64 * 16; i += 256) sW[i] = Wp[i];
        if (threadIdx.x < 16) sb[threadIdx.x] = bp[threadIdx.x];
        __syncthreads();
        int n = (blockIdx.x - NBB) * 256 + threadIdx.x;
        if (n >= NN) return;
        float acc[16];
#pragma unroll
        for (int k = 0; k < 16; ++k) acc[k] = sb[k];
        const float4* xr = (const float4*)(x + (size_t)n * 64);
#pragma unroll
        for (int j4 = 0; j4 < 16; ++j4) {
            float4 xv = xr[j4];
            const float* w = &sW[j4 * 4 * 16];
#pragma unroll
            for (int k = 0; k < 16; ++k) acc[k] += xv.x * w[k];
#pragma unroll
            for (int k = 0; k < 16; ++k) acc[k] += xv.y * w[16 + k];
#pragma unroll
            for (int k = 0; k < 16; ++k) acc[k] += xv.z * w[32 + k];
#pragma unroll
            for (int k = 0; k < 16; ++k) acc[k] += xv.w * w[48 + k];
        }
        float4* o = (float4*)(P1 + (size_t)n * 16);
        o[0] = make_float4(acc[0], acc[1], acc[2], acc[3]);
        o[1] = make_float4(acc[4], acc[5], acc[6], acc[7]);
        o[2] = make_float4(acc[8], acc[9], acc[10], acc[11]);
        o[3] = make_float4(acc[12], acc[13], acc[14], acc[15]);
    }
}

// ---- bin2 (self-scanning): per-block recompute of row prefixes + bucket bases,
//      then scatter records into bucket-grouped sp1. ----
__global__ void bin2_kernel(const int* __restrict__ ei, const float* __restrict__ ea,
                            const int* __restrict__ HM,
                            int* __restrict__ bstart,
                            int2* __restrict__ sp1) {
    __shared__ int s[512];
    __shared__ unsigned cur[NB];
    int tid = threadIdx.x;
    int blk = blockIdx.x;
    int total = 0, pre = 0;
    if (tid < NB) {
        const int* row = HM + tid * NBB;
        for (int k = 0; k < NBB; ++k) {
            if (k == blk) pre = total;
            total += row[k];
        }
    }
    s[tid] = total;
    __syncthreads();
#pragma unroll
    for (int off = 1; off < 512; off <<= 1) {
        int tmp = (tid >= off) ? s[tid - off] : 0;
        __syncthreads();
        s[tid] += tmp;
        __syncthreads();
    }
    if (tid < NB) {
        int base = s[tid] - total;
        cur[tid] = (unsigned)(base + pre);
        if (blk == 0) bstart[tid] = base;
    }
    if (blk == 0 && tid == 0) bstart[NB] = s[511];
    __syncthreads();
    int base = blk * EPB;
    for (int i = tid; i < EPB; i += 512) {
        int e = base + i;
        int d = ei[NE + e];
        int srcv = ei[e];
        int b = d >> BSHIFT;
        int dl = d & (BNODES - 1);
        unsigned pos = atomicAdd(&cur[b], 1u);
        sp1[pos] = make_int2(srcv | (dl << 16), __float_as_int(ea[e]));
    }
}

// ---- per-bucket counting sort by local node, DEGREE-RANKED ----
__global__ void sort_kernel(const int2* __restrict__ sp1,
                            const int* __restrict__ bstart,
                            int2* __restrict__ sp2,
                            int* __restrict__ start,
                            int* __restrict__ perm) {
    __shared__ unsigned hist[BNODES];
    __shared__ int s[256];
    __shared__ unsigned dcnt[64];
    __shared__ unsigned dcur[64];
    __shared__ int dlof[BNODES];
    __shared__ int soff[BNODES];
    __shared__ unsigned cur[BNODES];
    __shared__ int sdeg[BNODES];
    int tid = threadIdx.x;
    int b = blockIdx.x;
    int e0 = bstart[b], e1 = bstart[b + 1];
    if (tid < BNODES) hist[tid] = 0;
    if (tid < 64) dcnt[tid] = 0;
    __syncthreads();
    for (int i = e0 + tid; i < e1; i += 256) {
        int dl = (sp1[i].x >> 16) & (BNODES - 1);
        atomicAdd(&hist[dl], 1u);
    }
    __syncthreads();
    if (tid < BNODES) {
        int key = min((int)hist[tid], 63);
        atomicAdd(&dcnt[key], 1u);
    }
    __syncthreads();
    int v = (tid < 64) ? (int)dcnt[tid] : 0;
    s[tid] = v;
    __syncthreads();
#pragma unroll
    for (int off = 1; off < 64; off <<= 1) {
        int tmp = (tid >= off) ? s[tid - off] : 0;
        __syncthreads();
        s[tid] += tmp;
        __syncthreads();
    }
    if (tid < 64) dcur[tid] = (unsigned)(s[tid] - v);
    __syncthreads();
    if (tid < BNODES) {
        int key = min((int)hist[tid], 63);
        int rank = (int)atomicAdd(&dcur[key], 1u);
        dlof[rank] = tid;
    }
    __syncthreads();
    if (tid < BNODES) sdeg[tid] = (int)hist[dlof[tid]];
    __syncthreads();
    int v2 = (tid < BNODES) ? sdeg[tid] : 0;
    s[tid] = v2;
    __syncthreads();
#pragma unroll
    for (int off = 1; off < 128; off <<= 1) {
        int tmp = (tid >= off) ? s[tid - off] : 0;
        __syncthreads();
        s[tid] += tmp;
        __syncthreads();
    }
    if (tid < BNODES) {
        int off = s[tid] - v2;
        soff[tid] = off;
        start[b * BNODES + tid] = e0 + off;
        perm[b * BNODES + tid] = b * BNODES + dlof[tid];
    }
    __syncthreads();
    if (tid < BNODES) cur[dlof[tid]] = (unsigned)(e0 + soff[tid]);
    if (b == NB - 1 && tid == 0) start[NB * BNODES] = e1;
    __syncthreads();
    for (int i = e0 + tid; i < e1; i += 256) {
        int2 rec = sp1[i];
        int dl = (rec.x >> 16) & (BNODES - 1);
        int pos = (int)atomicAdd(&cur[dl], 1u);
        sp2[pos] = make_int2(rec.x & 0xFFFF, rec.y);
    }
}

// ---- fused gather-max + node MLP: 8 lanes/node, 2-way parity x 2-edge batch,
//      coalesced quad load + butterfly exchange-add, degree-ranked schedule ----
// R13-proven local optimum. Do NOT: edge-split (R6, 6x fetch), 16 lanes/node
// (R14, +17%), rec-coalesce batch (R15, +15%).
template <int MODE>
__global__ void __launch_bounds__(256, 4)
gather_kernel(const long long* __restrict__ sp, // [NE] rank-sorted (src|ea)
              const int* __restrict__ start,   // [NB*BNODES+1], rank-indexed
              const int* __restrict__ perm,    // [NB*BNODES] rank -> node id
              const float* __restrict__ Pin,   // [NN][16]
              const float* __restrict__ wl,    // [16]
              const float* __restrict__ Wn,    // [16][16]
              const float* __restrict__ bn,    // [16]
              const float* __restrict__ Wo,    // [16][16]
              const float* __restrict__ bo,    // [16]
              const float* __restrict__ Wpn,   // [17][16] (MODE 0)
              const float* __restrict__ bpn,   // [16] (MODE 0)
              float* __restrict__ out) {
    __shared__ float swl[16], sbn[16], sbo[16], sbpn[16];
    __shared__ float sWnT[16][17];      // transposed + padded: sWnT[c][j] = Wn[j][c]
    __shared__ float sWo[256], sWpn[256];
    __shared__ float sAgg[32][17];
    int tid = threadIdx.x;
    if (tid < 256) {
        sWnT[tid & 15][tid >> 4] = Wn[tid];
        sWo[tid] = Wo[tid];
        if (MODE == 0) sWpn[tid] = Wpn[tid];
    }
    if (tid < 16) {
        swl[tid] = wl[tid]; sbn[tid] = bn[tid]; sbo[tid] = bo[tid];
        if (MODE == 0) sbpn[tid] = bpn[tid];
    }
    __syncthreads();

    int l  = tid >> 3;       // local rank 0..31
    int g  = tid & 3;        // j-group / output-group 0..3
    int hi = (tid >> 2) & 1; // edge-parity quad 0/1
    int r = blockIdx.x * 32 + l;         // rank index
    int n = perm[r];                     // actual node id
    bool valid = (n < NN);

    float acc[4] = {-INFINITY, -INFINITY, -INFINITY, -INFINITY};
    int s0 = start[r], s1 = start[r + 1];

    float wl0 = swl[g * 4 + 0], wl1 = swl[g * 4 + 1],
          wl2 = swl[g * 4 + 2], wl3 = swl[g * 4 + 3];
    float bn0 = sbn[g * 4 + 0], bn1 = sbn[g * 4 + 1],
          bn2 = sbn[g * 4 + 2], bn3 = sbn[g * 4 + 3];
    bool g1 = (g & 1) != 0, g2 = (g & 2) != 0;

    // preload this lane's 64 Wn weights into registers (static indices only)
    float wreg[64];
#pragma unroll
    for (int c = 0; c < 16; ++c) {
#pragma unroll
        for (int j = 0; j < 4; ++j) wreg[c * 4 + j] = sWnT[c][g * 4 + j];
    }

    int s = s0 + hi;         // quad 0: even edges; quad 1: odd edges (stride 2)
    while (s < s1) {
        // batch of 2 edges: s and (s+2 clamped) — duplicate is a no-op under max
        int sB = (s + 2 < s1) ? (s + 2) : s;
        long long rA = sp[s];
        long long rB = sp[sB];
        int srcA = (int)(rA & 0xFFFFFFFFll);
        int srcB = (int)(rB & 0xFFFFFFFFll);
        float4 qA = ((const float4*)(Pin + (size_t)srcA * 16))[g];
        float4 qB = ((const float4*)(Pin + (size_t)srcB * 16))[g];
        float aA = __int_as_float((int)(rA >> 32));
        float aB = __int_as_float((int)(rB >> 32));
        s += 4;

#pragma unroll
        for (int e = 0; e < 2; ++e) {
            float4 cv = e ? qB : qA;
            float a = e ? aB : aA;
            float t0 = fmaxf(fmaf(a, wl0, cv.x), 0.0f);
            float t1 = fmaxf(fmaf(a, wl1, cv.y), 0.0f);
            float t2 = fmaxf(fmaf(a, wl2, cv.z), 0.0f);
            float t3 = fmaxf(fmaf(a, wl3, cv.w), 0.0f);
            float m[16];
#pragma unroll
            for (int c = 0; c < 16; ++c) {
                float o = t0 * wreg[c * 4 + 0];
                o = fmaf(t1, wreg[c * 4 + 1], o);
                o = fmaf(t2, wreg[c * 4 + 2], o);
                o = fmaf(t3, wreg[c * 4 + 3], o);
                m[c] = o;
            }
            // butterfly step 1 (xor 2)
            float h[8];
#pragma unroll
            for (int c = 0; c < 8; ++c) {
                float send = g2 ? m[c] : m[c + 8];
                float recv = __shfl_xor(send, 2, 64);
                h[c] = (g2 ? m[c + 8] : m[c]) + recv;
            }
            // butterfly step 2 (xor 1)
            float send, recv, r0, r1, r2, r3;
            send = g1 ? h[0] : h[4]; recv = __shfl_xor(send, 1, 64); r0 = (g1 ? h[4] : h[0]) + recv;
            send = g1 ? h[1] : h[5]; recv = __shfl_xor(send, 1, 64); r1 = (g1 ? h[5] : h[1]) + recv;
            send = g1 ? h[2] : h[6]; recv = __shfl_xor(send, 1, 64); r2 = (g1 ? h[6] : h[2]) + recv;
            send = g1 ? h[3] : h[7]; recv = __shfl_xor(send, 1, 64); r3 = (g1 ? h[7] : h[3]) + recv;
            acc[0] = fmaxf(acc[0], r0 + bn0);
            acc[1] = fmaxf(acc[1], r1 + bn1);
            acc[2] = fmaxf(acc[2], r2 + bn2);
            acc[3] = fmaxf(acc[3], r3 + bn3);
        }
    }
    // merge the two edge-parity quads (lanes l*8+g and l*8+4+g)
#pragma unroll
    for (int q = 0; q < 4; ++q) acc[q] = fmaxf(acc[q], __shfl_xor(acc[q], 4, 64));

    bool empty = (s1 == s0);
#pragma unroll
    for (int q = 0; q < 4; ++q) sAgg[l][g * 4 + q] = empty ? 0.0f : acc[q];
    __syncthreads();

    if (MODE == 0) {
        float h[4];
#pragma unroll
        for (int q = 0; q < 4; ++q) {
            int c = g * 4 + q;
            float o = sbo[c];
#pragma unroll
            for (int j = 0; j < 16; ++j) o = fmaf(sAgg[l][j], sWo[j * 16 + c], o);
            h[q] = elu1(elu1(o));
        }
        __syncthreads();
        if (hi == 0) {
#pragma unroll
            for (int q = 0; q < 4; ++q) sAgg[l][g * 4 + q] = h[q];
        }
        __syncthreads();
        float p[4];
#pragma unroll
        for (int q = 0; q < 4; ++q) {
            int c = g * 4 + q;
            float o = sbpn[c];
#pragma unroll
            for (int k = 0; k < 16; ++k) o = fmaf(sAgg[l][k], sWpn[k * 16 + c], o);
            p[q] = o;
        }
        if (valid && hi == 0) {
            float4* op = (float4*)(out + (size_t)n * 16 + g * 4);
            *op = make_float4(p[0], p[1], p[2], p[3]);
        }
    } else {
        float oo[4];
#pragma unroll
        for (int q = 0; q < 4; ++q) {
            int c = g * 4 + q;
            float o = sbo[c];
#pragma unroll
            for (int j = 0; j < 16; ++j) o = fmaf(sAgg[l][j], sWo[j * 16 + c], o);
            oo[q] = o;
        }
        __syncthreads();
        if (hi == 0) {
#pragma unroll
            for (int q = 0; q < 4; ++q) sAgg[l][g * 4 + q] = oo[q];
        }
        __syncthreads();
        float mx = -INFINITY;
#pragma unroll
        for (int j = 0; j < 16; ++j) mx = fmaxf(mx, sAgg[l][j]);
        float sum = 0.0f;
#pragma unroll
        for (int j = 0; j < 16; ++j) sum += expf(sAgg[l][j] - mx);
        float ls = logf(sum) + mx;
        if (valid && hi == 0) {
            float4* op = (float4*)(out + (size_t)n * 16 + g * 4);
            *op = make_float4(oo[0] - ls, oo[1] - ls, oo[2] - ls, oo[3] - ls);
        }
    }
}

extern "C" void kernel_launch(void* const* d_in, const int* in_sizes, int n_in,
                              void* d_out, int out_size, void* d_ws, size_t ws_size,
                              hipStream_t stream) {
    const float* x         = (const float*)d_in[0];
    const float* edge_attr = (const float*)d_in[1];
    const int*   edge_index= (const int*)  d_in[2];
    const float* W_pre1 = (const float*)d_in[3];
    const float* b_pre1 = (const float*)d_in[4];
    const float* W_net1 = (const float*)d_in[5];
    const float* b_net1 = (const float*)d_in[6];
    const float* W_out1 = (const float*)d_in[7];
    const float* b_out1 = (const float*)d_in[8];
    const float* W_pre2 = (const float*)d_in[9];
    const float* b_pre2 = (const float*)d_in[10];
    const float* W_net2 = (const float*)d_in[11];
    const float* b_net2 = (const float*)d_in[12];
    const float* W_out2 = (const float*)d_in[13];
    const float* b_out2 = (const float*)d_in[14];

    char* ws = (char*)d_ws;
    int2*  sp1    = (int2*) (ws);                   // 6,400,000 B
    int2*  sp2    = (int2*) (ws + 6400000);         // 6,400,000 B
    float* P1     = (float*)(ws + 12800000);        // 3,200,000 B
    float* P2     = (float*)(ws + 16000000);        // 3,200,000 B
    int*   HM     = (int*)  (ws + 19200000);        // 312,800 B
    int*   bstart = (int*)  (ws + 19520000);        // 1,568 B
    int*   start  = (int*)  (ws + 19528000);        // (NB*128+1)*4 = 200,196 B
    int*   perm   = (int*)  (ws + 19728256);        // NB*128*4 = 200,192 B

    const int GATH_BLOCKS = (NB * BNODES) / 32;     // 1564 (rank space)

    // ----- setup: bin1 histogram + pre1 projection, concurrent -----
    setup_kernel<<<NBB + PRE_BLOCKS, 256, 0, stream>>>(edge_index, HM, x, W_pre1, b_pre1, P1);
    // ----- bin2: self-scan (replaces row_scan + scan_rows) + scatter -----
    bin2_kernel<<<NBB, 512, 0, stream>>>(edge_index, edge_attr, HM, bstart, sp1);
    sort_kernel<<<NB, 256, 0, stream>>>(sp1, bstart, sp2, start, perm);

    // ----- layer 1 -----
    gather_kernel<0><<<GATH_BLOCKS, 256, 0, stream>>>((const long long*)sp2, start, perm, P1,
        W_pre1 + 64 * 16, W_net1, b_net1, W_out1, b_out1, W_pre2, b_pre2, P2);

    // ----- layer 2 -----
    gather_kernel<1><<<GATH_BLOCKS, 256, 0, stream>>>((const long long*)sp2, start, perm, P2,
        W_pre2 + 16 * 16, W_net2, b_net2, W_out2, b_out2, nullptr, nullptr,
        (float*)d_out);
}